// Round 1
// baseline (543.796 us; speedup 1.0000x reference)
//
#include <hip/hip_runtime.h>
#include <hip/hip_bf16.h>

#define DIM 1152
#define NHEAD 12
#define NKVH 4
#define HDIM 96
#define BATCH 16
#define NTOK 1024
#define M_TOK (BATCH*NTOK)   // 16384
#define O1 1920              // 1152 q + 384 k + 384 v
typedef unsigned short ushort_t;
typedef __attribute__((ext_vector_type(8))) short bf16x8;
typedef __attribute__((ext_vector_type(4))) float f32x4;
typedef __attribute__((ext_vector_type(8))) unsigned short ushort8;
typedef __attribute__((ext_vector_type(4))) unsigned short ushort4v;

__device__ __forceinline__ ushort_t f2bf(float f) {
    union { float f; unsigned u; } v; v.f = f;
    unsigned u = v.u;
    unsigned r = (u + 0x7fffu + ((u >> 16) & 1u)) >> 16;
    return (ushort_t)r;
}
__device__ __forceinline__ float bf2f(ushort_t h) {
    union { unsigned u; float f; } v; v.u = ((unsigned)h) << 16;
    return v.f;
}

// ---------------- generic 128x128 bf16 MFMA mainloop (A[M][K], Bt[N][K]) ----------------
__device__ __forceinline__ void gemm_main(const ushort_t* __restrict__ A,
                                          const ushort_t* __restrict__ Bt,
                                          int K, int m0, int n0,
                                          ushort_t As[128][56], ushort_t Bs[128][56],
                                          f32x4 acc[4][4])
{
    const int tid = threadIdx.x;
    const int lane = tid & 63, wave = tid >> 6;
    const int wr = wave >> 1, wc = wave & 1;
    const int l15 = lane & 15, g = lane >> 4;
    const int q4 = tid & 3, rr = tid >> 2;

    for (int kt = 0; kt < K / 32; ++kt) {
        __syncthreads();
        for (int r = 0; r < 2; ++r) {
            int row = r * 64 + rr;
            ushort8 av = *(const ushort8*)(A + (size_t)(m0 + row) * K + kt * 32 + q4 * 8);
            *(ushort8*)(&As[row][q4 * 8]) = av;
            ushort8 bv = *(const ushort8*)(Bt + (size_t)(n0 + row) * K + kt * 32 + q4 * 8);
            *(ushort8*)(&Bs[row][q4 * 8]) = bv;
        }
        __syncthreads();
        bf16x8 af[4], bfr[4];
        #pragma unroll
        for (int m = 0; m < 4; ++m)
            af[m] = *(const bf16x8*)(&As[wr * 64 + m * 16 + l15][g * 8]);
        #pragma unroll
        for (int n = 0; n < 4; ++n)
            bfr[n] = *(const bf16x8*)(&Bs[wc * 64 + n * 16 + l15][g * 8]);
        #pragma unroll
        for (int m = 0; m < 4; ++m)
            #pragma unroll
            for (int n = 0; n < 4; ++n)
                acc[m][n] = __builtin_amdgcn_mfma_f32_16x16x32_bf16(af[m], bfr[n], acc[m][n], 0, 0, 0);
    }
}

// ---------------- K1: fused qkv projection ----------------
__global__ __launch_bounds__(256) void gemm1_kernel(
    const ushort_t* __restrict__ xb, const ushort_t* __restrict__ w1b,
    const float* __restrict__ wq_b, const float* __restrict__ wkv_b,
    ushort_t* __restrict__ qr, ushort_t* __restrict__ krT, ushort_t* __restrict__ vT)
{
    __shared__ ushort_t As[128][56];
    __shared__ ushort_t Bs[128][56];
    const int m0 = blockIdx.x * 128;
    const int n0 = blockIdx.y * 128;
    f32x4 acc[4][4] = {};
    gemm_main(xb, w1b, DIM, m0, n0, As, Bs, acc);

    const int tid = threadIdx.x;
    const int lane = tid & 63, wave = tid >> 6;
    const int wr = wave >> 1, wc = wave & 1;
    const int l15 = lane & 15, g = lane >> 4;
    const int region = (n0 < 1152) ? 0 : (n0 < 1536 ? 1 : 2);

    #pragma unroll
    for (int m = 0; m < 4; ++m) {
        int tokb = m0 + wr * 64 + m * 16 + g * 4;
        int b_ = tokb >> 10;
        #pragma unroll
        for (int n = 0; n < 4; ++n) {
            int o = n0 + wc * 64 + n * 16 + l15;
            float bias = (o < 1152) ? wq_b[o] : wkv_b[o - 1152];
            if (region == 0) {
                #pragma unroll
                for (int j = 0; j < 4; ++j) {
                    float y = acc[m][n][j] + bias;
                    qr[(size_t)(tokb + j) * DIM + o] = f2bf(fmaxf(y, 0.f));
                }
            } else {
                int oo = o - (region == 1 ? 1152 : 1536);
                size_t base = ((size_t)(b_ * 4 + oo / 96) * 96 + (oo % 96)) * 1024 + (tokb & 1023);
                ushort4v pk;
                #pragma unroll
                for (int j = 0; j < 4; ++j) {
                    float y = acc[m][n][j] + bias;
                    if (region == 1) y = fmaxf(y, 0.f);
                    pk[j] = f2bf(y);
                }
                if (region == 1) *(ushort4v*)(krT + base) = pk;
                else             *(ushort4v*)(vT + base) = pk;
            }
        }
    }
}

// ---------------- K2: focus norms -> scale factors ----------------
__global__ __launch_bounds__(256) void norm_kernel(const ushort_t* __restrict__ qr,
                                                   const ushort_t* __restrict__ krT,
                                                   float* __restrict__ scale_q,
                                                   float* __restrict__ scale_k)
{
    int gblk = blockIdx.x, tid = threadIdx.x;
    float s2 = 0.f, s6 = 0.f;
    if (gblk < 192) {
        int b_ = gblk / 12, h = gblk % 12;
        const ushort_t* base = qr + (size_t)b_ * 1024 * DIM + h * 96;
        for (int i = tid; i < 1024 * 96; i += 256) {
            int nrow = i / 96, d = i - nrow * 96;
            float a = bf2f(base[(size_t)nrow * DIM + d]);
            float a2 = a * a;
            s2 += a2; s6 += a2 * a2 * a2;
        }
    } else {
        const ushort_t* base = krT + (size_t)(gblk - 192) * 96 * 1024;
        for (int i = tid; i < 96 * 1024; i += 256) {
            float a = bf2f(base[i]);
            float a2 = a * a;
            s2 += a2; s6 += a2 * a2 * a2;
        }
    }
    #pragma unroll
    for (int off = 32; off; off >>= 1) {
        s2 += __shfl_down(s2, off);
        s6 += __shfl_down(s6, off);
    }
    __shared__ float red[2][4];
    int lane = tid & 63, wave = tid >> 6;
    if (lane == 0) { red[0][wave] = s2; red[1][wave] = s6; }
    __syncthreads();
    if (tid == 0) {
        float t2 = red[0][0] + red[0][1] + red[0][2] + red[0][3];
        float t6 = red[1][0] + red[1][1] + red[1][2] + red[1][3];
        float an = sqrtf(t2), ap = sqrtf(t6);
        if (ap == 0.f) ap = 1e-12f;
        float s = an / ap;
        if (gblk < 192) scale_q[gblk] = s; else scale_k[gblk - 192] = s;
    }
}

// ---------------- K3: kv = relu(k)^3^T @ v  (per b,kvh; partial over token chunks) ----------------
__global__ __launch_bounds__(384) void kv_kernel(const ushort_t* __restrict__ krT,
                                                 const ushort_t* __restrict__ vT,
                                                 float* __restrict__ kvbuf)
{
    int tid = threadIdx.x, lane = tid & 63, wave = tid >> 6;
    int nc = blockIdx.x, kvh = blockIdx.y, b_ = blockIdx.z;
    size_t base = (size_t)(b_ * 4 + kvh) * 96 * 1024;
    int l15 = lane & 15, gq = lane >> 4;
    f32x4 acc[6] = {};
    int d = wave * 16 + l15;
    const ushort_t* arow = krT + base + (size_t)d * 1024;
    for (int kt = 0; kt < 8; ++kt) {
        int n = nc * 256 + kt * 32 + gq * 8;
        ushort8 ar = *(const ushort8*)(arow + n);
        bf16x8 af;
        #pragma unroll
        for (int j = 0; j < 8; ++j) {
            float f = bf2f(ar[j]);
            af[j] = (short)f2bf(f * f * f);
        }
        #pragma unroll
        for (int e = 0; e < 6; ++e) {
            const ushort_t* brow = vT + base + (size_t)(e * 16 + l15) * 1024;
            ushort8 bu = *(const ushort8*)(brow + n);
            bf16x8 bfr = __builtin_bit_cast(bf16x8, bu);
            acc[e] = __builtin_amdgcn_mfma_f32_16x16x32_bf16(af, bfr, acc[e], 0, 0, 0);
        }
    }
    #pragma unroll
    for (int e = 0; e < 6; ++e) {
        int col = e * 16 + l15;
        #pragma unroll
        for (int j = 0; j < 4; ++j) {
            int row = wave * 16 + gq * 4 + j;
            atomicAdd(&kvbuf[((size_t)(b_ * 4 + kvh) * 96 + row) * 96 + col], acc[e][j]);
        }
    }
}

// ---------------- K4: depthwise 3x3 conv on v (channel-major grid) ----------------
__global__ __launch_bounds__(256) void dwconv_kernel(const ushort_t* __restrict__ vT,
                                                     const float* __restrict__ dwc_w,
                                                     const float* __restrict__ dwc_b,
                                                     ushort_t* __restrict__ cv)
{
    int c = blockIdx.x, b_ = blockIdx.y;
    const ushort_t* in = vT + (size_t)(b_ * 384 + c) * 1024;
    float w[9];
    #pragma unroll
    for (int i = 0; i < 9; ++i) w[i] = dwc_w[c * 9 + i];
    float bias = dwc_b[c];
    for (int p = threadIdx.x; p < 1024; p += 256) {
        int y = p >> 5, x = p & 31;
        float s = bias;
        #pragma unroll
        for (int ky = 0; ky < 3; ++ky) {
            int yy = y + ky - 1;
            if (yy < 0 || yy > 31) continue;
            #pragma unroll
            for (int kx = 0; kx < 3; ++kx) {
                int xx = x + kx - 1;
                if (xx < 0 || xx > 31) continue;
                s += w[ky * 3 + kx] * bf2f(in[yy * 32 + xx]);
            }
        }
        cv[(size_t)(b_ * 384 + c) * 1024 + p] = f2bf(s);
    }
}

// ---------------- K5: out = s * relu(q)^3 @ kv + conv ----------------
__global__ __launch_bounds__(256) void attn_kernel(const ushort_t* __restrict__ qr,
                                                   const float* __restrict__ kvbuf,
                                                   const ushort_t* __restrict__ cv,
                                                   const float* __restrict__ scale_q,
                                                   const float* __restrict__ scale_k,
                                                   ushort_t* __restrict__ obuf)
{
    __shared__ ushort_t BsT[96][104];   // kv^T as bf16: BsT[e][d]
    int tid = threadIdx.x, lane = tid & 63, wave = tid >> 6;
    int mt = blockIdx.x, h = blockIdx.y, b_ = blockIdx.z;
    int kvh = h & 3;
    const float* kvp = kvbuf + (size_t)(b_ * 4 + kvh) * 96 * 96;
    for (int i = tid; i < 96 * 96; i += 256) {
        int d = i / 96, e = i - d * 96;
        BsT[e][d] = f2bf(kvp[i]);
    }
    __syncthreads();
    int l15 = lane & 15, gq = lane >> 4;
    int t0 = mt * 128 + wave * 32;
    f32x4 acc[2][6] = {};
    for (int kt = 0; kt < 3; ++kt) {
        bf16x8 af[2];
        #pragma unroll
        for (int m = 0; m < 2; ++m) {
            int tok = t0 + m * 16 + l15;
            ushort8 ar = *(const ushort8*)(qr + (size_t)(b_ * 1024 + tok) * DIM + h * 96 + kt * 32 + gq * 8);
            #pragma unroll
            for (int j = 0; j < 8; ++j) {
                float f = bf2f(ar[j]);
                af[m][j] = (short)f2bf(f * f * f);
            }
        }
        #pragma unroll
        for (int n = 0; n < 6; ++n) {
            bf16x8 bfr = *(const bf16x8*)(&BsT[n * 16 + l15][kt * 32 + gq * 8]);
            #pragma unroll
            for (int m = 0; m < 2; ++m)
                acc[m][n] = __builtin_amdgcn_mfma_f32_16x16x32_bf16(af[m], bfr, acc[m][n], 0, 0, 0);
        }
    }
    float s = scale_q[b_ * 12 + h] * scale_k[b_ * 4 + kvh];
    #pragma unroll
    for (int m = 0; m < 2; ++m) {
        int tokb = t0 + m * 16 + gq * 4;
        #pragma unroll
        for (int n = 0; n < 6; ++n) {
            int e = n * 16 + l15;
            ushort4v c4 = *(const ushort4v*)(cv + ((size_t)(b_ * 384 + kvh * 96 + e)) * 1024 + tokb);
            #pragma unroll
            for (int j = 0; j < 4; ++j) {
                float val = acc[m][n][j] * s + bf2f(c4[j]);
                obuf[(size_t)(b_ * 1024 + tokb + j) * DIM + h * 96 + e] = f2bf(val);
            }
        }
    }
}

// ---------------- K6: final projection (f32 out) ----------------
__global__ __launch_bounds__(256) void proj_kernel(const ushort_t* __restrict__ obuf,
                                                   const ushort_t* __restrict__ projb,
                                                   const float* __restrict__ proj_b,
                                                   float* __restrict__ out)
{
    __shared__ ushort_t As[128][56];
    __shared__ ushort_t Bs[128][56];
    const int m0 = blockIdx.x * 128;
    const int n0 = blockIdx.y * 128;
    f32x4 acc[4][4] = {};
    gemm_main(obuf, projb, DIM, m0, n0, As, Bs, acc);

    const int tid = threadIdx.x;
    const int lane = tid & 63, wave = tid >> 6;
    const int wr = wave >> 1, wc = wave & 1;
    const int l15 = lane & 15, g = lane >> 4;
    #pragma unroll
    for (int m = 0; m < 4; ++m) {
        int tokb = m0 + wr * 64 + m * 16 + g * 4;
        #pragma unroll
        for (int n = 0; n < 4; ++n) {
            int o = n0 + wc * 64 + n * 16 + l15;
            float bias = proj_b[o];
            #pragma unroll
            for (int j = 0; j < 4; ++j)
                out[(size_t)(tokb + j) * DIM + o] = acc[m][n][j] + bias;
        }
    }
}

// ---------------- prep: f32 -> bf16 bulk convert ----------------
__global__ void cvt_f32_bf16(const float* __restrict__ src, ushort_t* __restrict__ dst, int n8)
{
    int i = blockIdx.x * 256 + threadIdx.x;
    if (i >= n8) return;
    const float4* s = (const float4*)src + (size_t)i * 2;
    float4 a = s[0], b4 = s[1];
    ushort8 o;
    o[0] = f2bf(a.x);  o[1] = f2bf(a.y);  o[2] = f2bf(a.z);  o[3] = f2bf(a.w);
    o[4] = f2bf(b4.x); o[5] = f2bf(b4.y); o[6] = f2bf(b4.z); o[7] = f2bf(b4.w);
    *(ushort8*)(dst + (size_t)i * 8) = o;
}

extern "C" void kernel_launch(void* const* d_in, const int* in_sizes, int n_in,
                              void* d_out, int out_size, void* d_ws, size_t ws_size,
                              hipStream_t stream)
{
    const float* x      = (const float*)d_in[0];
    const float* wq_w   = (const float*)d_in[1];
    const float* wq_b   = (const float*)d_in[2];
    const float* wkv_w  = (const float*)d_in[3];
    const float* wkv_b  = (const float*)d_in[4];
    const float* dwc_w  = (const float*)d_in[5];
    const float* dwc_b  = (const float*)d_in[6];
    const float* proj_w = (const float*)d_in[7];
    const float* proj_b = (const float*)d_in[8];
    float* out = (float*)d_out;

    char* ws = (char*)d_ws;
    size_t off = 0;
    auto alloc = [&](size_t bytes) {
        void* p = ws + off;
        off += (bytes + 255) & ~(size_t)255;
        return p;
    };
    ushort_t* xb    = (ushort_t*)alloc((size_t)M_TOK * DIM * 2);   // reused as obuf later
    ushort_t* w1b   = (ushort_t*)alloc((size_t)O1 * DIM * 2);
    ushort_t* projb = (ushort_t*)alloc((size_t)DIM * DIM * 2);
    ushort_t* qr    = (ushort_t*)alloc((size_t)M_TOK * DIM * 2);
    ushort_t* krT   = (ushort_t*)alloc((size_t)BATCH * 4 * 96 * 1024 * 2);
    ushort_t* vT    = (ushort_t*)alloc((size_t)BATCH * 4 * 96 * 1024 * 2);
    float*    kvbuf = (float*)alloc((size_t)BATCH * 4 * 96 * 96 * 4);
    ushort_t* cv    = (ushort_t*)alloc((size_t)BATCH * 384 * 1024 * 2);
    float*    scale_q = (float*)alloc(192 * 4);
    float*    scale_k = (float*)alloc(64 * 4);
    ushort_t* obuf = xb;

    cvt_f32_bf16<<<(M_TOK * DIM / 8 + 255) / 256, 256, 0, stream>>>(x, xb, M_TOK * DIM / 8);
    cvt_f32_bf16<<<(DIM * DIM / 8 + 255) / 256, 256, 0, stream>>>(wq_w, w1b, DIM * DIM / 8);
    cvt_f32_bf16<<<(768 * DIM / 8 + 255) / 256, 256, 0, stream>>>(wkv_w, w1b + (size_t)DIM * DIM, 768 * DIM / 8);
    cvt_f32_bf16<<<(DIM * DIM / 8 + 255) / 256, 256, 0, stream>>>(proj_w, projb, DIM * DIM / 8);
    hipMemsetAsync(kvbuf, 0, (size_t)BATCH * 4 * 96 * 96 * 4, stream);

    gemm1_kernel<<<dim3(M_TOK / 128, O1 / 128), 256, 0, stream>>>(xb, w1b, wq_b, wkv_b, qr, krT, vT);
    norm_kernel<<<256, 256, 0, stream>>>(qr, krT, scale_q, scale_k);
    kv_kernel<<<dim3(4, 4, BATCH), 384, 0, stream>>>(krT, vT, kvbuf);
    dwconv_kernel<<<dim3(384, BATCH), 256, 0, stream>>>(vT, dwc_w, dwc_b, cv);
    attn_kernel<<<dim3(8, 12, BATCH), 256, 0, stream>>>(qr, kvbuf, cv, scale_q, scale_k, obuf);
    proj_kernel<<<dim3(M_TOK / 128, DIM / 128), 256, 0, stream>>>(obuf, projb, proj_b, out);
}

// Round 4
// 422.633 us; speedup vs baseline: 1.2867x; 1.2867x over previous
//
#include <hip/hip_runtime.h>
#include <hip/hip_bf16.h>

#define DIM 1152
#define NHEAD 12
#define NKVH 4
#define HDIM 96
#define BATCH 16
#define NTOK 1024
#define M_TOK (BATCH*NTOK)   // 16384
#define O1 1920              // 1152 q + 384 k + 384 v
typedef unsigned short ushort_t;
typedef __attribute__((ext_vector_type(8))) short bf16x8;
typedef __attribute__((ext_vector_type(4))) float f32x4;
typedef __attribute__((ext_vector_type(8))) unsigned short ushort8;
typedef __attribute__((ext_vector_type(4))) unsigned short ushort4v;

__device__ __forceinline__ ushort_t f2bf(float f) {
    union { float f; unsigned u; } v; v.f = f;
    unsigned u = v.u;
    unsigned r = (u + 0x7fffu + ((u >> 16) & 1u)) >> 16;
    return (ushort_t)r;
}
__device__ __forceinline__ float bf2f(ushort_t h) {
    union { unsigned u; float f; } v; v.u = ((unsigned)h) << 16;
    return v.f;
}

// async 16B global->LDS (direct DMA, no VGPR round trip). LDS dest is
// wave-uniform base + lane*16B; global src is per-lane.
__device__ __forceinline__ void async_load16(const ushort_t* g, ushort_t* l) {
    __builtin_amdgcn_global_load_lds(
        (const __attribute__((address_space(1))) unsigned*)g,
        (__attribute__((address_space(3))) unsigned*)l, 16, 0, 0);
}

// ---------------- m97-style 128x128 bf16 MFMA mainloop (A[M][K], Bt[N][K]) ----------------
// LDS linear [128][32] per operand; staging via global_load_lds width=16.
__device__ __forceinline__ void gemm_main(const ushort_t* __restrict__ A,
                                          const ushort_t* __restrict__ Bt,
                                          int K, int m0, int n0,
                                          ushort_t* As, ushort_t* Bs,
                                          f32x4 acc[4][4])
{
    const int tid = threadIdx.x;
    const int lane = tid & 63, wave = tid >> 6;
    const int wr = wave >> 1, wc = wave & 1;
    const int l15 = lane & 15, g = lane >> 4;
    // staging geometry: wave w stages rows [w*32, w*32+32) of each tile.
    // one wave-load = 64 lanes * 16B = 16 rows (row = lane>>2, col8 = lane&3).
    const int srow = lane >> 2;
    const int scol = (lane & 3) * 8;
    const ushort_t* Ag = A + (size_t)(m0 + wave * 32 + srow) * K + scol;
    const ushort_t* Bg = Bt + (size_t)(n0 + wave * 32 + srow) * K + scol;
    ushort_t* Asl = As + wave * 1024;   // 32 rows * 32 cols
    ushort_t* Bsl = Bs + wave * 1024;
    const size_t rstep = (size_t)16 * K;

    for (int kt = 0; kt < K / 32; ++kt) {
        __syncthreads();                  // prior iter's ds_reads done
        async_load16(Ag, Asl);
        async_load16(Ag + rstep, Asl + 512);
        async_load16(Bg, Bsl);
        async_load16(Bg + rstep, Bsl + 512);
        Ag += 32; Bg += 32;
        __syncthreads();                  // vmcnt(0) drain: tile resident
        bf16x8 af[4], bfr[4];
        #pragma unroll
        for (int m = 0; m < 4; ++m)
            af[m] = *(const bf16x8*)(As + (wr * 64 + m * 16 + l15) * 32 + g * 8);
        #pragma unroll
        for (int n = 0; n < 4; ++n)
            bfr[n] = *(const bf16x8*)(Bs + (wc * 64 + n * 16 + l15) * 32 + g * 8);
        #pragma unroll
        for (int m = 0; m < 4; ++m)
            #pragma unroll
            for (int n = 0; n < 4; ++n)
                acc[m][n] = __builtin_amdgcn_mfma_f32_16x16x32_bf16(af[m], bfr[n], acc[m][n], 0, 0, 0);
    }
}

// ---------------- K1: fused qkv projection ----------------
__global__ __launch_bounds__(256) void gemm1_kernel(
    const ushort_t* __restrict__ xb, const ushort_t* __restrict__ w1b,
    const float* __restrict__ wq_b, const float* __restrict__ wkv_b,
    ushort_t* __restrict__ qr, ushort_t* __restrict__ krT, ushort_t* __restrict__ vT)
{
    __shared__ ushort_t As[128 * 32];
    __shared__ ushort_t Bs[128 * 32];
    const int m0 = blockIdx.x * 128;
    const int n0 = blockIdx.y * 128;
    f32x4 acc[4][4] = {};
    gemm_main(xb, w1b, DIM, m0, n0, As, Bs, acc);

    const int tid = threadIdx.x;
    const int lane = tid & 63, wave = tid >> 6;
    const int wr = wave >> 1, wc = wave & 1;
    const int l15 = lane & 15, g = lane >> 4;
    const int region = (n0 < 1152) ? 0 : (n0 < 1536 ? 1 : 2);

    #pragma unroll
    for (int m = 0; m < 4; ++m) {
        int tokb = m0 + wr * 64 + m * 16 + g * 4;
        int b_ = tokb >> 10;
        #pragma unroll
        for (int n = 0; n < 4; ++n) {
            int o = n0 + wc * 64 + n * 16 + l15;
            float bias = (o < 1152) ? wq_b[o] : wkv_b[o - 1152];
            if (region == 0) {
                #pragma unroll
                for (int j = 0; j < 4; ++j) {
                    float y = acc[m][n][j] + bias;
                    qr[(size_t)(tokb + j) * DIM + o] = f2bf(fmaxf(y, 0.f));
                }
            } else {
                int oo = o - (region == 1 ? 1152 : 1536);
                size_t base = ((size_t)(b_ * 4 + oo / 96) * 96 + (oo % 96)) * 1024 + (tokb & 1023);
                ushort4v pk;
                #pragma unroll
                for (int j = 0; j < 4; ++j) {
                    float y = acc[m][n][j] + bias;
                    if (region == 1) y = fmaxf(y, 0.f);
                    pk[j] = f2bf(y);
                }
                if (region == 1) *(ushort4v*)(krT + base) = pk;
                else             *(ushort4v*)(vT + base) = pk;
            }
        }
    }
}

// ---------------- K2: focus norms -> scale factors ----------------
__global__ __launch_bounds__(256) void norm_kernel(const ushort_t* __restrict__ qr,
                                                   const ushort_t* __restrict__ krT,
                                                   float* __restrict__ scale_q,
                                                   float* __restrict__ scale_k)
{
    int gblk = blockIdx.x, tid = threadIdx.x;
    float s2 = 0.f, s6 = 0.f;
    if (gblk < 192) {
        int b_ = gblk / 12, h = gblk % 12;
        const ushort_t* base = qr + (size_t)b_ * 1024 * DIM + h * 96;
        // 1024 rows x 12 ushort8 vectors per row
        for (int i = tid; i < 1024 * 12; i += 256) {
            int nrow = i / 12, dv = (i - nrow * 12) * 8;
            ushort8 v = *(const ushort8*)(base + (size_t)nrow * DIM + dv);
            #pragma unroll
            for (int j = 0; j < 8; ++j) {
                float a = bf2f(v[j]);
                float a2 = a * a;
                s2 += a2; s6 += a2 * a2 * a2;
            }
        }
    } else {
        const ushort_t* base = krT + (size_t)(gblk - 192) * 96 * 1024;
        for (int i = tid; i < 96 * 1024 / 8; i += 256) {
            ushort8 v = *(const ushort8*)(base + (size_t)i * 8);
            #pragma unroll
            for (int j = 0; j < 8; ++j) {
                float a = bf2f(v[j]);
                float a2 = a * a;
                s2 += a2; s6 += a2 * a2 * a2;
            }
        }
    }
    #pragma unroll
    for (int off = 32; off; off >>= 1) {
        s2 += __shfl_down(s2, off);
        s6 += __shfl_down(s6, off);
    }
    __shared__ float red[2][4];
    int lane = tid & 63, wave = tid >> 6;
    if (lane == 0) { red[0][wave] = s2; red[1][wave] = s6; }
    __syncthreads();
    if (tid == 0) {
        float t2 = red[0][0] + red[0][1] + red[0][2] + red[0][3];
        float t6 = red[1][0] + red[1][1] + red[1][2] + red[1][3];
        float an = sqrtf(t2), ap = sqrtf(t6);
        if (ap == 0.f) ap = 1e-12f;
        float s = an / ap;
        if (gblk < 192) scale_q[gblk] = s; else scale_k[gblk - 192] = s;
    }
}

// ---------------- K3: kv = relu(k)^3^T @ v  (per b,kvh; partial over token chunks) ----------------
__global__ __launch_bounds__(384) void kv_kernel(const ushort_t* __restrict__ krT,
                                                 const ushort_t* __restrict__ vT,
                                                 float* __restrict__ kvbuf)
{
    int tid = threadIdx.x, lane = tid & 63, wave = tid >> 6;
    int nc = blockIdx.x, kvh = blockIdx.y, b_ = blockIdx.z;
    size_t base = (size_t)(b_ * 4 + kvh) * 96 * 1024;
    int l15 = lane & 15, gq = lane >> 4;
    f32x4 acc[6] = {};
    int d = wave * 16 + l15;
    const ushort_t* arow = krT + base + (size_t)d * 1024;
    for (int kt = 0; kt < 8; ++kt) {
        int n = nc * 256 + kt * 32 + gq * 8;
        ushort8 ar = *(const ushort8*)(arow + n);
        bf16x8 af;
        #pragma unroll
        for (int j = 0; j < 8; ++j) {
            float f = bf2f(ar[j]);
            af[j] = (short)f2bf(f * f * f);
        }
        #pragma unroll
        for (int e = 0; e < 6; ++e) {
            const ushort_t* brow = vT + base + (size_t)(e * 16 + l15) * 1024;
            ushort8 bu = *(const ushort8*)(brow + n);
            bf16x8 bfr = __builtin_bit_cast(bf16x8, bu);
            acc[e] = __builtin_amdgcn_mfma_f32_16x16x32_bf16(af, bfr, acc[e], 0, 0, 0);
        }
    }
    #pragma unroll
    for (int e = 0; e < 6; ++e) {
        int col = e * 16 + l15;
        #pragma unroll
        for (int j = 0; j < 4; ++j) {
            int row = wave * 16 + gq * 4 + j;
            atomicAdd(&kvbuf[((size_t)(b_ * 4 + kvh) * 96 + row) * 96 + col], acc[e][j]);
        }
    }
}

// ---------------- K4: depthwise 3x3 conv on v (channel-major grid) ----------------
__global__ __launch_bounds__(256) void dwconv_kernel(const ushort_t* __restrict__ vT,
                                                     const float* __restrict__ dwc_w,
                                                     const float* __restrict__ dwc_b,
                                                     ushort_t* __restrict__ cv)
{
    int c = blockIdx.x, b_ = blockIdx.y;
    const ushort_t* in = vT + (size_t)(b_ * 384 + c) * 1024;
    float w[9];
    #pragma unroll
    for (int i = 0; i < 9; ++i) w[i] = dwc_w[c * 9 + i];
    float bias = dwc_b[c];
    for (int p = threadIdx.x; p < 1024; p += 256) {
        int y = p >> 5, x = p & 31;
        float s = bias;
        #pragma unroll
        for (int ky = 0; ky < 3; ++ky) {
            int yy = y + ky - 1;
            if (yy < 0 || yy > 31) continue;
            #pragma unroll
            for (int kx = 0; kx < 3; ++kx) {
                int xx = x + kx - 1;
                if (xx < 0 || xx > 31) continue;
                s += w[ky * 3 + kx] * bf2f(in[yy * 32 + xx]);
            }
        }
        cv[(size_t)(b_ * 384 + c) * 1024 + p] = f2bf(s);
    }
}

// ---------------- K5: out = s * relu(q)^3 @ kv + conv ----------------
__global__ __launch_bounds__(256) void attn_kernel(const ushort_t* __restrict__ qr,
                                                   const float* __restrict__ kvbuf,
                                                   const ushort_t* __restrict__ cv,
                                                   const float* __restrict__ scale_q,
                                                   const float* __restrict__ scale_k,
                                                   ushort_t* __restrict__ obuf)
{
    __shared__ ushort_t BsT[96][104];   // kv^T as bf16: BsT[e][d]
    int tid = threadIdx.x, lane = tid & 63, wave = tid >> 6;
    int mt = blockIdx.x, h = blockIdx.y, b_ = blockIdx.z;
    int kvh = h & 3;
    const float* kvp = kvbuf + (size_t)(b_ * 4 + kvh) * 96 * 96;
    for (int i = tid; i < 96 * 96; i += 256) {
        int d = i / 96, e = i - d * 96;
        BsT[e][d] = f2bf(kvp[i]);
    }
    __syncthreads();
    int l15 = lane & 15, gq = lane >> 4;
    int t0 = mt * 128 + wave * 32;
    f32x4 acc[2][6] = {};
    for (int kt = 0; kt < 3; ++kt) {
        bf16x8 af[2];
        #pragma unroll
        for (int m = 0; m < 2; ++m) {
            int tok = t0 + m * 16 + l15;
            ushort8 ar = *(const ushort8*)(qr + (size_t)(b_ * 1024 + tok) * DIM + h * 96 + kt * 32 + gq * 8);
            #pragma unroll
            for (int j = 0; j < 8; ++j) {
                float f = bf2f(ar[j]);
                af[m][j] = (short)f2bf(f * f * f);
            }
        }
        #pragma unroll
        for (int n = 0; n < 6; ++n) {
            bf16x8 bfr = *(const bf16x8*)(&BsT[n * 16 + l15][kt * 32 + gq * 8]);
            #pragma unroll
            for (int m = 0; m < 2; ++m)
                acc[m][n] = __builtin_amdgcn_mfma_f32_16x16x32_bf16(af[m], bfr, acc[m][n], 0, 0, 0);
        }
    }
    float s = scale_q[b_ * 12 + h] * scale_k[b_ * 4 + kvh];
    #pragma unroll
    for (int m = 0; m < 2; ++m) {
        int tokb = t0 + m * 16 + gq * 4;
        #pragma unroll
        for (int n = 0; n < 6; ++n) {
            int e = n * 16 + l15;
            ushort4v c4 = *(const ushort4v*)(cv + ((size_t)(b_ * 384 + kvh * 96 + e)) * 1024 + tokb);
            #pragma unroll
            for (int j = 0; j < 4; ++j) {
                float val = acc[m][n][j] * s + bf2f(c4[j]);
                obuf[(size_t)(b_ * 1024 + tokb + j) * DIM + h * 96 + e] = f2bf(val);
            }
        }
    }
}

// ---------------- K6: final projection (f32 out) ----------------
__global__ __launch_bounds__(256) void proj_kernel(const ushort_t* __restrict__ obuf,
                                                   const ushort_t* __restrict__ projb,
                                                   const float* __restrict__ proj_b,
                                                   float* __restrict__ out)
{
    __shared__ ushort_t As[128 * 32];
    __shared__ ushort_t Bs[128 * 32];
    const int m0 = blockIdx.x * 128;
    const int n0 = blockIdx.y * 128;
    f32x4 acc[4][4] = {};
    gemm_main(obuf, projb, DIM, m0, n0, As, Bs, acc);

    const int tid = threadIdx.x;
    const int lane = tid & 63, wave = tid >> 6;
    const int wr = wave >> 1, wc = wave & 1;
    const int l15 = lane & 15, g = lane >> 4;
    #pragma unroll
    for (int m = 0; m < 4; ++m) {
        int tokb = m0 + wr * 64 + m * 16 + g * 4;
        #pragma unroll
        for (int n = 0; n < 4; ++n) {
            int o = n0 + wc * 64 + n * 16 + l15;
            float bias = proj_b[o];
            #pragma unroll
            for (int j = 0; j < 4; ++j)
                out[(size_t)(tokb + j) * DIM + o] = acc[m][n][j] + bias;
        }
    }
}

// ---------------- prep: f32 -> bf16 bulk convert ----------------
__global__ void cvt_f32_bf16(const float* __restrict__ src, ushort_t* __restrict__ dst, int n8)
{
    int i = blockIdx.x * 256 + threadIdx.x;
    if (i >= n8) return;
    const float4* s = (const float4*)src + (size_t)i * 2;
    float4 a = s[0], b4 = s[1];
    ushort8 o;
    o[0] = f2bf(a.x);  o[1] = f2bf(a.y);  o[2] = f2bf(a.z);  o[3] = f2bf(a.w);
    o[4] = f2bf(b4.x); o[5] = f2bf(b4.y); o[6] = f2bf(b4.z); o[7] = f2bf(b4.w);
    *(ushort8*)(dst + (size_t)i * 8) = o;
}

extern "C" void kernel_launch(void* const* d_in, const int* in_sizes, int n_in,
                              void* d_out, int out_size, void* d_ws, size_t ws_size,
                              hipStream_t stream)
{
    const float* x      = (const float*)d_in[0];
    const float* wq_w   = (const float*)d_in[1];
    const float* wq_b   = (const float*)d_in[2];
    const float* wkv_w  = (const float*)d_in[3];
    const float* wkv_b  = (const float*)d_in[4];
    const float* dwc_w  = (const float*)d_in[5];
    const float* dwc_b  = (const float*)d_in[6];
    const float* proj_w = (const float*)d_in[7];
    const float* proj_b = (const float*)d_in[8];
    float* out = (float*)d_out;

    char* ws = (char*)d_ws;
    size_t off = 0;
    auto alloc = [&](size_t bytes) {
        void* p = ws + off;
        off += (bytes + 255) & ~(size_t)255;
        return p;
    };
    ushort_t* xb    = (ushort_t*)alloc((size_t)M_TOK * DIM * 2);   // reused as obuf later
    ushort_t* w1b   = (ushort_t*)alloc((size_t)O1 * DIM * 2);
    ushort_t* projb = (ushort_t*)alloc((size_t)DIM * DIM * 2);
    ushort_t* qr    = (ushort_t*)alloc((size_t)M_TOK * DIM * 2);
    ushort_t* krT   = (ushort_t*)alloc((size_t)BATCH * 4 * 96 * 1024 * 2);
    ushort_t* vT    = (ushort_t*)alloc((size_t)BATCH * 4 * 96 * 1024 * 2);
    float*    kvbuf = (float*)alloc((size_t)BATCH * 4 * 96 * 96 * 4);
    ushort_t* cv    = (ushort_t*)alloc((size_t)BATCH * 384 * 1024 * 2);
    float*    scale_q = (float*)alloc(192 * 4);
    float*    scale_k = (float*)alloc(64 * 4);
    ushort_t* obuf = xb;

    cvt_f32_bf16<<<(M_TOK * DIM / 8 + 255) / 256, 256, 0, stream>>>(x, xb, M_TOK * DIM / 8);
    cvt_f32_bf16<<<(DIM * DIM / 8 + 255) / 256, 256, 0, stream>>>(wq_w, w1b, DIM * DIM / 8);
    cvt_f32_bf16<<<(768 * DIM / 8 + 255) / 256, 256, 0, stream>>>(wkv_w, w1b + (size_t)DIM * DIM, 768 * DIM / 8);
    cvt_f32_bf16<<<(DIM * DIM / 8 + 255) / 256, 256, 0, stream>>>(proj_w, projb, DIM * DIM / 8);
    hipMemsetAsync(kvbuf, 0, (size_t)BATCH * 4 * 96 * 96 * 4, stream);

    gemm1_kernel<<<dim3(M_TOK / 128, O1 / 128), 256, 0, stream>>>(xb, w1b, wq_b, wkv_b, qr, krT, vT);
    norm_kernel<<<256, 256, 0, stream>>>(qr, krT, scale_q, scale_k);
    kv_kernel<<<dim3(4, 4, BATCH), 384, 0, stream>>>(krT, vT, kvbuf);
    dwconv_kernel<<<dim3(384, BATCH), 256, 0, stream>>>(vT, dwc_w, dwc_b, cv);
    attn_kernel<<<dim3(8, 12, BATCH), 256, 0, stream>>>(qr, kvbuf, cv, scale_q, scale_k, obuf);
    proj_kernel<<<dim3(M_TOK / 128, DIM / 128), 256, 0, stream>>>(obuf, projb, proj_b, out);
}

// Round 6
// 422.404 us; speedup vs baseline: 1.2874x; 1.0005x over previous
//
#include <hip/hip_runtime.h>
#include <hip/hip_bf16.h>

#define DIM 1152
#define NHEAD 12
#define NKVH 4
#define HDIM 96
#define BATCH 16
#define NTOK 1024
#define M_TOK (BATCH*NTOK)   // 16384
#define O1 1920              // 1152 q + 384 k + 384 v
typedef unsigned short ushort_t;
typedef __attribute__((ext_vector_type(8))) short bf16x8;
typedef __attribute__((ext_vector_type(4))) float f32x4;
typedef __attribute__((ext_vector_type(8))) unsigned short ushort8;
typedef __attribute__((ext_vector_type(4))) unsigned short ushort4v;

__device__ __forceinline__ ushort_t f2bf(float f) {
    union { float f; unsigned u; } v; v.f = f;
    unsigned u = v.u;
    unsigned r = (u + 0x7fffu + ((u >> 16) & 1u)) >> 16;
    return (ushort_t)r;
}
__device__ __forceinline__ float bf2f(ushort_t h) {
    union { unsigned u; float f; } v; v.u = ((unsigned)h) << 16;
    return v.f;
}

// async 16B global->LDS (direct DMA, no VGPR round trip). LDS dest is
// wave-uniform base + lane*16B; global src is per-lane.
__device__ __forceinline__ void async_load16(const ushort_t* g, ushort_t* l) {
    __builtin_amdgcn_global_load_lds(
        (const __attribute__((address_space(1))) unsigned*)g,
        (__attribute__((address_space(3))) unsigned*)l, 16, 0, 0);
}

// ---------------- 128x128 bf16 MFMA mainloop, 2-phase double-buffered ----------------
// T3-minimum pipeline: prefetch K-step kt+1 into buf^1 BEFORE computing buf,
// one barrier per K-step. LDS: 2 x [128][32] per operand (32 KB total).
__device__ __forceinline__ void gemm_main(const ushort_t* __restrict__ A,
                                          const ushort_t* __restrict__ Bt,
                                          int K, int m0, int n0,
                                          ushort_t* As, ushort_t* Bs,
                                          f32x4 acc[4][4])
{
    const int tid = threadIdx.x;
    const int lane = tid & 63, wave = tid >> 6;
    const int wr = wave >> 1, wc = wave & 1;
    const int l15 = lane & 15, g = lane >> 4;
    // staging geometry: wave w stages rows [w*32, w*32+32) of each tile.
    // one wave-load = 64 lanes * 16B = 16 rows (row = lane>>2, col8 = lane&3).
    const int srow = lane >> 2;
    const int scol = (lane & 3) * 8;
    const ushort_t* Ag = A + (size_t)(m0 + wave * 32 + srow) * K + scol;
    const ushort_t* Bg = Bt + (size_t)(n0 + wave * 32 + srow) * K + scol;
    ushort_t* Asl = As + wave * 1024;   // wave's 32 rows x 32 cols within a buffer
    ushort_t* Bsl = Bs + wave * 1024;
    const size_t rstep = (size_t)16 * K;
    const int NK = K / 32;

    // prologue: stage tile 0 into buffer 0
    async_load16(Ag, Asl);
    async_load16(Ag + rstep, Asl + 512);
    async_load16(Bg, Bsl);
    async_load16(Bg + rstep, Bsl + 512);
    __syncthreads();   // drains vmcnt(0): tile 0 resident for all waves

    int cur = 0;
    for (int kt = 0; kt < NK; ++kt) {
        const bool more = (kt + 1) < NK;
        if (more) {
            // issue next tile's loads into the other buffer; they fly during MFMA
            const int nb = (cur ^ 1) * 4096;
            const ushort_t* Agn = Ag + (size_t)(kt + 1) * 32;
            const ushort_t* Bgn = Bg + (size_t)(kt + 1) * 32;
            async_load16(Agn, Asl + nb);
            async_load16(Agn + rstep, Asl + nb + 512);
            async_load16(Bgn, Bsl + nb);
            async_load16(Bgn + rstep, Bsl + nb + 512);
        }
        const ushort_t* Asr = As + cur * 4096;
        const ushort_t* Bsr = Bs + cur * 4096;
        bf16x8 af[4], bfr[4];
        #pragma unroll
        for (int m = 0; m < 4; ++m)
            af[m] = *(const bf16x8*)(Asr + (wr * 64 + m * 16 + l15) * 32 + g * 8);
        #pragma unroll
        for (int n = 0; n < 4; ++n)
            bfr[n] = *(const bf16x8*)(Bsr + (wc * 64 + n * 16 + l15) * 32 + g * 8);
        #pragma unroll
        for (int m = 0; m < 4; ++m)
            #pragma unroll
            for (int n = 0; n < 4; ++n)
                acc[m][n] = __builtin_amdgcn_mfma_f32_16x16x32_bf16(af[m], bfr[n], acc[m][n], 0, 0, 0);
        if (more) {
            __syncthreads();   // drains prefetch (vmcnt) + this tile's ds_reads (lgkm)
            cur ^= 1;
        }
    }
}

// ---------------- K1: fused qkv projection ----------------
__global__ __launch_bounds__(256) void gemm1_kernel(
    const ushort_t* __restrict__ xb, const ushort_t* __restrict__ w1b,
    const float* __restrict__ wq_b, const float* __restrict__ wkv_b,
    ushort_t* __restrict__ qr, ushort_t* __restrict__ krT, ushort_t* __restrict__ vT)
{
    __shared__ ushort_t As[2 * 128 * 32];
    __shared__ ushort_t Bs[2 * 128 * 32];
    const int m0 = blockIdx.x * 128;
    const int n0 = blockIdx.y * 128;
    f32x4 acc[4][4] = {};
    gemm_main(xb, w1b, DIM, m0, n0, As, Bs, acc);

    const int tid = threadIdx.x;
    const int lane = tid & 63, wave = tid >> 6;
    const int wr = wave >> 1, wc = wave & 1;
    const int l15 = lane & 15, g = lane >> 4;
    const int region = (n0 < 1152) ? 0 : (n0 < 1536 ? 1 : 2);

    #pragma unroll
    for (int m = 0; m < 4; ++m) {
        int tokb = m0 + wr * 64 + m * 16 + g * 4;
        int b_ = tokb >> 10;
        #pragma unroll
        for (int n = 0; n < 4; ++n) {
            int o = n0 + wc * 64 + n * 16 + l15;
            float bias = (o < 1152) ? wq_b[o] : wkv_b[o - 1152];
            if (region == 0) {
                #pragma unroll
                for (int j = 0; j < 4; ++j) {
                    float y = acc[m][n][j] + bias;
                    qr[(size_t)(tokb + j) * DIM + o] = f2bf(fmaxf(y, 0.f));
                }
            } else {
                int oo = o - (region == 1 ? 1152 : 1536);
                size_t base = ((size_t)(b_ * 4 + oo / 96) * 96 + (oo % 96)) * 1024 + (tokb & 1023);
                ushort4v pk;
                #pragma unroll
                for (int j = 0; j < 4; ++j) {
                    float y = acc[m][n][j] + bias;
                    if (region == 1) y = fmaxf(y, 0.f);
                    pk[j] = f2bf(y);
                }
                if (region == 1) *(ushort4v*)(krT + base) = pk;
                else             *(ushort4v*)(vT + base) = pk;
            }
        }
    }
}

// ---------------- K2: focus norms -> scale factors ----------------
__global__ __launch_bounds__(256) void norm_kernel(const ushort_t* __restrict__ qr,
                                                   const ushort_t* __restrict__ krT,
                                                   float* __restrict__ scale_q,
                                                   float* __restrict__ scale_k)
{
    int gblk = blockIdx.x, tid = threadIdx.x;
    float s2 = 0.f, s6 = 0.f;
    if (gblk < 192) {
        int b_ = gblk / 12, h = gblk % 12;
        const ushort_t* base = qr + (size_t)b_ * 1024 * DIM + h * 96;
        // 1024 rows x 12 ushort8 vectors per row
        for (int i = tid; i < 1024 * 12; i += 256) {
            int nrow = i / 12, dv = (i - nrow * 12) * 8;
            ushort8 v = *(const ushort8*)(base + (size_t)nrow * DIM + dv);
            #pragma unroll
            for (int j = 0; j < 8; ++j) {
                float a = bf2f(v[j]);
                float a2 = a * a;
                s2 += a2; s6 += a2 * a2 * a2;
            }
        }
    } else {
        const ushort_t* base = krT + (size_t)(gblk - 192) * 96 * 1024;
        for (int i = tid; i < 96 * 1024 / 8; i += 256) {
            ushort8 v = *(const ushort8*)(base + (size_t)i * 8);
            #pragma unroll
            for (int j = 0; j < 8; ++j) {
                float a = bf2f(v[j]);
                float a2 = a * a;
                s2 += a2; s6 += a2 * a2 * a2;
            }
        }
    }
    #pragma unroll
    for (int off = 32; off; off >>= 1) {
        s2 += __shfl_down(s2, off);
        s6 += __shfl_down(s6, off);
    }
    __shared__ float red[2][4];
    int lane = tid & 63, wave = tid >> 6;
    if (lane == 0) { red[0][wave] = s2; red[1][wave] = s6; }
    __syncthreads();
    if (tid == 0) {
        float t2 = red[0][0] + red[0][1] + red[0][2] + red[0][3];
        float t6 = red[1][0] + red[1][1] + red[1][2] + red[1][3];
        float an = sqrtf(t2), ap = sqrtf(t6);
        if (ap == 0.f) ap = 1e-12f;
        float s = an / ap;
        if (gblk < 192) scale_q[gblk] = s; else scale_k[gblk - 192] = s;
    }
}

// ---------------- K3: kv = relu(k)^3^T @ v  (per b,kvh; partial over token chunks) ----------------
__global__ __launch_bounds__(384) void kv_kernel(const ushort_t* __restrict__ krT,
                                                 const ushort_t* __restrict__ vT,
                                                 float* __restrict__ kvbuf)
{
    int tid = threadIdx.x, lane = tid & 63, wave = tid >> 6;
    int nc = blockIdx.x, kvh = blockIdx.y, b_ = blockIdx.z;
    size_t base = (size_t)(b_ * 4 + kvh) * 96 * 1024;
    int l15 = lane & 15, gq = lane >> 4;
    f32x4 acc[6] = {};
    int d = wave * 16 + l15;
    const ushort_t* arow = krT + base + (size_t)d * 1024;
    for (int kt = 0; kt < 8; ++kt) {
        int n = nc * 256 + kt * 32 + gq * 8;
        ushort8 ar = *(const ushort8*)(arow + n);
        bf16x8 af;
        #pragma unroll
        for (int j = 0; j < 8; ++j) {
            float f = bf2f(ar[j]);
            af[j] = (short)f2bf(f * f * f);
        }
        #pragma unroll
        for (int e = 0; e < 6; ++e) {
            const ushort_t* brow = vT + base + (size_t)(e * 16 + l15) * 1024;
            ushort8 bu = *(const ushort8*)(brow + n);
            bf16x8 bfr = __builtin_bit_cast(bf16x8, bu);
            acc[e] = __builtin_amdgcn_mfma_f32_16x16x32_bf16(af, bfr, acc[e], 0, 0, 0);
        }
    }
    #pragma unroll
    for (int e = 0; e < 6; ++e) {
        int col = e * 16 + l15;
        #pragma unroll
        for (int j = 0; j < 4; ++j) {
            int row = wave * 16 + gq * 4 + j;
            atomicAdd(&kvbuf[((size_t)(b_ * 4 + kvh) * 96 + row) * 96 + col], acc[e][j]);
        }
    }
}

// ---------------- K4: depthwise 3x3 conv on v (channel-major grid) ----------------
__global__ __launch_bounds__(256) void dwconv_kernel(const ushort_t* __restrict__ vT,
                                                     const float* __restrict__ dwc_w,
                                                     const float* __restrict__ dwc_b,
                                                     ushort_t* __restrict__ cv)
{
    int c = blockIdx.x, b_ = blockIdx.y;
    const ushort_t* in = vT + (size_t)(b_ * 384 + c) * 1024;
    float w[9];
    #pragma unroll
    for (int i = 0; i < 9; ++i) w[i] = dwc_w[c * 9 + i];
    float bias = dwc_b[c];
    for (int p = threadIdx.x; p < 1024; p += 256) {
        int y = p >> 5, x = p & 31;
        float s = bias;
        #pragma unroll
        for (int ky = 0; ky < 3; ++ky) {
            int yy = y + ky - 1;
            if (yy < 0 || yy > 31) continue;
            #pragma unroll
            for (int kx = 0; kx < 3; ++kx) {
                int xx = x + kx - 1;
                if (xx < 0 || xx > 31) continue;
                s += w[ky * 3 + kx] * bf2f(in[yy * 32 + xx]);
            }
        }
        cv[(size_t)(b_ * 384 + c) * 1024 + p] = f2bf(s);
    }
}

// ---------------- K5: out = s * relu(q)^3 @ kv + conv ----------------
__global__ __launch_bounds__(256) void attn_kernel(const ushort_t* __restrict__ qr,
                                                   const float* __restrict__ kvbuf,
                                                   const ushort_t* __restrict__ cv,
                                                   const float* __restrict__ scale_q,
                                                   const float* __restrict__ scale_k,
                                                   ushort_t* __restrict__ obuf)
{
    __shared__ ushort_t BsT[96][104];   // kv^T as bf16: BsT[e][d]
    int tid = threadIdx.x, lane = tid & 63, wave = tid >> 6;
    int mt = blockIdx.x, h = blockIdx.y, b_ = blockIdx.z;
    int kvh = h & 3;
    const float* kvp = kvbuf + (size_t)(b_ * 4 + kvh) * 96 * 96;
    for (int i = tid; i < 96 * 96; i += 256) {
        int d = i / 96, e = i - d * 96;
        BsT[e][d] = f2bf(kvp[i]);
    }
    __syncthreads();
    int l15 = lane & 15, gq = lane >> 4;
    int t0 = mt * 128 + wave * 32;
    f32x4 acc[2][6] = {};
    for (int kt = 0; kt < 3; ++kt) {
        bf16x8 af[2];
        #pragma unroll
        for (int m = 0; m < 2; ++m) {
            int tok = t0 + m * 16 + l15;
            ushort8 ar = *(const ushort8*)(qr + (size_t)(b_ * 1024 + tok) * DIM + h * 96 + kt * 32 + gq * 8);
            #pragma unroll
            for (int j = 0; j < 8; ++j) {
                float f = bf2f(ar[j]);
                af[m][j] = (short)f2bf(f * f * f);
            }
        }
        #pragma unroll
        for (int n = 0; n < 6; ++n) {
            bf16x8 bfr = *(const bf16x8*)(&BsT[n * 16 + l15][kt * 32 + gq * 8]);
            #pragma unroll
            for (int m = 0; m < 2; ++m)
                acc[m][n] = __builtin_amdgcn_mfma_f32_16x16x32_bf16(af[m], bfr, acc[m][n], 0, 0, 0);
        }
    }
    float s = scale_q[b_ * 12 + h] * scale_k[b_ * 4 + kvh];
    #pragma unroll
    for (int m = 0; m < 2; ++m) {
        int tokb = t0 + m * 16 + gq * 4;
        #pragma unroll
        for (int n = 0; n < 6; ++n) {
            int e = n * 16 + l15;
            ushort4v c4 = *(const ushort4v*)(cv + ((size_t)(b_ * 384 + kvh * 96 + e)) * 1024 + tokb);
            #pragma unroll
            for (int j = 0; j < 4; ++j) {
                float val = acc[m][n][j] * s + bf2f(c4[j]);
                obuf[(size_t)(b_ * 1024 + tokb + j) * DIM + h * 96 + e] = f2bf(val);
            }
        }
    }
}

// ---------------- K6: final projection (f32 out) ----------------
__global__ __launch_bounds__(256) void proj_kernel(const ushort_t* __restrict__ obuf,
                                                   const ushort_t* __restrict__ projb,
                                                   const float* __restrict__ proj_b,
                                                   float* __restrict__ out)
{
    __shared__ ushort_t As[2 * 128 * 32];
    __shared__ ushort_t Bs[2 * 128 * 32];
    const int m0 = blockIdx.x * 128;
    const int n0 = blockIdx.y * 128;
    f32x4 acc[4][4] = {};
    gemm_main(obuf, projb, DIM, m0, n0, As, Bs, acc);

    const int tid = threadIdx.x;
    const int lane = tid & 63, wave = tid >> 6;
    const int wr = wave >> 1, wc = wave & 1;
    const int l15 = lane & 15, g = lane >> 4;
    #pragma unroll
    for (int m = 0; m < 4; ++m) {
        int tokb = m0 + wr * 64 + m * 16 + g * 4;
        #pragma unroll
        for (int n = 0; n < 4; ++n) {
            int o = n0 + wc * 64 + n * 16 + l15;
            float bias = proj_b[o];
            #pragma unroll
            for (int j = 0; j < 4; ++j)
                out[(size_t)(tokb + j) * DIM + o] = acc[m][n][j] + bias;
        }
    }
}

// ---------------- prep: f32 -> bf16 bulk convert ----------------
__global__ void cvt_f32_bf16(const float* __restrict__ src, ushort_t* __restrict__ dst, int n8)
{
    int i = blockIdx.x * 256 + threadIdx.x;
    if (i >= n8) return;
    const float4* s = (const float4*)src + (size_t)i * 2;
    float4 a = s[0], b4 = s[1];
    ushort8 o;
    o[0] = f2bf(a.x);  o[1] = f2bf(a.y);  o[2] = f2bf(a.z);  o[3] = f2bf(a.w);
    o[4] = f2bf(b4.x); o[5] = f2bf(b4.y); o[6] = f2bf(b4.z); o[7] = f2bf(b4.w);
    *(ushort8*)(dst + (size_t)i * 8) = o;
}

extern "C" void kernel_launch(void* const* d_in, const int* in_sizes, int n_in,
                              void* d_out, int out_size, void* d_ws, size_t ws_size,
                              hipStream_t stream)
{
    const float* x      = (const float*)d_in[0];
    const float* wq_w   = (const float*)d_in[1];
    const float* wq_b   = (const float*)d_in[2];
    const float* wkv_w  = (const float*)d_in[3];
    const float* wkv_b  = (const float*)d_in[4];
    const float* dwc_w  = (const float*)d_in[5];
    const float* dwc_b  = (const float*)d_in[6];
    const float* proj_w = (const float*)d_in[7];
    const float* proj_b = (const float*)d_in[8];
    float* out = (float*)d_out;

    char* ws = (char*)d_ws;
    size_t off = 0;
    auto alloc = [&](size_t bytes) {
        void* p = ws + off;
        off += (bytes + 255) & ~(size_t)255;
        return p;
    };
    ushort_t* xb    = (ushort_t*)alloc((size_t)M_TOK * DIM * 2);   // reused as obuf later
    ushort_t* w1b   = (ushort_t*)alloc((size_t)O1 * DIM * 2);
    ushort_t* projb = (ushort_t*)alloc((size_t)DIM * DIM * 2);
    ushort_t* qr    = (ushort_t*)alloc((size_t)M_TOK * DIM * 2);
    ushort_t* krT   = (ushort_t*)alloc((size_t)BATCH * 4 * 96 * 1024 * 2);
    ushort_t* vT    = (ushort_t*)alloc((size_t)BATCH * 4 * 96 * 1024 * 2);
    float*    kvbuf = (float*)alloc((size_t)BATCH * 4 * 96 * 96 * 4);
    ushort_t* cv    = (ushort_t*)alloc((size_t)BATCH * 384 * 1024 * 2);
    float*    scale_q = (float*)alloc(192 * 4);
    float*    scale_k = (float*)alloc(64 * 4);
    ushort_t* obuf = xb;

    cvt_f32_bf16<<<(M_TOK * DIM / 8 + 255) / 256, 256, 0, stream>>>(x, xb, M_TOK * DIM / 8);
    cvt_f32_bf16<<<(DIM * DIM / 8 + 255) / 256, 256, 0, stream>>>(wq_w, w1b, DIM * DIM / 8);
    cvt_f32_bf16<<<(768 * DIM / 8 + 255) / 256, 256, 0, stream>>>(wkv_w, w1b + (size_t)DIM * DIM, 768 * DIM / 8);
    cvt_f32_bf16<<<(DIM * DIM / 8 + 255) / 256, 256, 0, stream>>>(proj_w, projb, DIM * DIM / 8);
    hipMemsetAsync(kvbuf, 0, (size_t)BATCH * 4 * 96 * 96 * 4, stream);

    gemm1_kernel<<<dim3(M_TOK / 128, O1 / 128), 256, 0, stream>>>(xb, w1b, wq_b, wkv_b, qr, krT, vT);
    norm_kernel<<<256, 256, 0, stream>>>(qr, krT, scale_q, scale_k);
    kv_kernel<<<dim3(4, 4, BATCH), 384, 0, stream>>>(krT, vT, kvbuf);
    dwconv_kernel<<<dim3(384, BATCH), 256, 0, stream>>>(vT, dwc_w, dwc_b, cv);
    attn_kernel<<<dim3(8, 12, BATCH), 256, 0, stream>>>(qr, kvbuf, cv, scale_q, scale_k, obuf);
    proj_kernel<<<dim3(M_TOK / 128, DIM / 128), 256, 0, stream>>>(obuf, projb, proj_b, out);
}

// Round 8
// 405.247 us; speedup vs baseline: 1.3419x; 1.0423x over previous
//
#include <hip/hip_runtime.h>
#include <hip/hip_bf16.h>

#define DIM 1152
#define NHEAD 12
#define NKVH 4
#define HDIM 96
#define BATCH 16
#define NTOK 1024
#define M_TOK (BATCH*NTOK)   // 16384
#define O1 1920              // 1152 q + 384 k + 384 v
typedef unsigned short ushort_t;
typedef __attribute__((ext_vector_type(8))) short bf16x8;
typedef __attribute__((ext_vector_type(4))) float f32x4;
typedef __attribute__((ext_vector_type(8))) unsigned short ushort8;
typedef __attribute__((ext_vector_type(4))) unsigned short ushort4v;

__device__ __forceinline__ ushort_t f2bf(float f) {
    union { float f; unsigned u; } v; v.f = f;
    unsigned u = v.u;
    unsigned r = (u + 0x7fffu + ((u >> 16) & 1u)) >> 16;
    return (ushort_t)r;
}
__device__ __forceinline__ float bf2f(ushort_t h) {
    union { unsigned u; float f; } v; v.u = ((unsigned)h) << 16;
    return v.f;
}

// async 16B global->LDS (direct DMA). LDS dest = wave-uniform base + lane*16B.
__device__ __forceinline__ void async_load16(const ushort_t* g, ushort_t* l) {
    __builtin_amdgcn_global_load_lds(
        (const __attribute__((address_space(1))) unsigned*)g,
        (__attribute__((address_space(3))) unsigned*)l, 16, 0, 0);
}

// ---------------- 128x128 bf16 MFMA mainloop ----------------
// T3+T4: 3 LDS buffers, prefetch 2 tiles ahead, counted s_waitcnt vmcnt(4)
// (never drain to 0 mid-loop) + raw s_barrier (one per K-step).
// Per iter: vmcnt(4)->barrier->stage L_{t+2}->ds_read+MFMA on buf[t%3].
// Writers of buf b (iter t, post-barrier) vs readers (iter t-1, pre-barrier,
// retired via lgkmcnt before each wave's MFMA) are barrier-separated.
__device__ __forceinline__ void gemm_main(const ushort_t* __restrict__ A,
                                          const ushort_t* __restrict__ Bt,
                                          int K, int m0, int n0,
                                          ushort_t* As, ushort_t* Bs,
                                          f32x4 acc[4][4])
{
    const int tid = threadIdx.x;
    const int lane = tid & 63, wave = tid >> 6;
    const int wr = wave >> 1, wc = wave & 1;
    const int l15 = lane & 15, g = lane >> 4;
    // staging: wave w stages rows [w*32, w*32+32); one wave-load = 16 rows.
    const int srow = lane >> 2;
    const int scol = (lane & 3) * 8;
    const ushort_t* Ag = A + (size_t)(m0 + wave * 32 + srow) * K + scol;
    const ushort_t* Bg = Bt + (size_t)(n0 + wave * 32 + srow) * K + scol;
    const size_t rstep = (size_t)16 * K;
    const int NK = K / 32;
    const int woff = wave * 1024;

    auto stage = [&](int t, int buf) {
        const ushort_t* Agt = Ag + (size_t)t * 32;
        const ushort_t* Bgt = Bg + (size_t)t * 32;
        ushort_t* Ad = As + buf * 4096 + woff;
        ushort_t* Bd = Bs + buf * 4096 + woff;
        async_load16(Agt, Ad);
        async_load16(Agt + rstep, Ad + 512);
        async_load16(Bgt, Bd);
        async_load16(Bgt + rstep, Bd + 512);
    };

    // prologue: 2 tiles in flight
    stage(0, 0);
    stage(1, 1);

    int cc = 0;   // buffer for tile kt       (= kt % 3)
    int pc = 2;   // buffer for tile kt + 2   (= (kt+2) % 3)
    for (int kt = 0; kt < NK; ++kt) {
        if (kt + 1 < NK) {
            // oldest 4 loads (tile kt) landed; newest 4 (tile kt+1) keep flying
            asm volatile("s_waitcnt vmcnt(4)" ::: "memory");
        } else {
            asm volatile("s_waitcnt vmcnt(0)" ::: "memory");
        }
        __builtin_amdgcn_s_barrier();
        if (kt + 2 < NK) stage(kt + 2, pc);

        const ushort_t* Asr = As + cc * 4096;
        const ushort_t* Bsr = Bs + cc * 4096;
        bf16x8 af[4], bfr[4];
        #pragma unroll
        for (int m = 0; m < 4; ++m)
            af[m] = *(const bf16x8*)(Asr + (wr * 64 + m * 16 + l15) * 32 + g * 8);
        #pragma unroll
        for (int n = 0; n < 4; ++n)
            bfr[n] = *(const bf16x8*)(Bsr + (wc * 64 + n * 16 + l15) * 32 + g * 8);
        #pragma unroll
        for (int m = 0; m < 4; ++m)
            #pragma unroll
            for (int n = 0; n < 4; ++n)
                acc[m][n] = __builtin_amdgcn_mfma_f32_16x16x32_bf16(af[m], bfr[n], acc[m][n], 0, 0, 0);

        cc = (cc == 2) ? 0 : cc + 1;
        pc = (pc == 2) ? 0 : pc + 1;
    }
}

// ---------------- K1: fused qkv projection ----------------
__global__ __launch_bounds__(256) void gemm1_kernel(
    const ushort_t* __restrict__ xb, const ushort_t* __restrict__ w1b,
    const float* __restrict__ wq_b, const float* __restrict__ wkv_b,
    ushort_t* __restrict__ qr, ushort_t* __restrict__ krT, ushort_t* __restrict__ vT)
{
    __shared__ ushort_t As[3 * 128 * 32];
    __shared__ ushort_t Bs[3 * 128 * 32];
    const int m0 = blockIdx.x * 128;
    const int n0 = blockIdx.y * 128;
    f32x4 acc[4][4] = {};
    gemm_main(xb, w1b, DIM, m0, n0, As, Bs, acc);

    const int tid = threadIdx.x;
    const int lane = tid & 63, wave = tid >> 6;
    const int wr = wave >> 1, wc = wave & 1;
    const int l15 = lane & 15, g = lane >> 4;
    const int region = (n0 < 1152) ? 0 : (n0 < 1536 ? 1 : 2);

    #pragma unroll
    for (int m = 0; m < 4; ++m) {
        int tokb = m0 + wr * 64 + m * 16 + g * 4;
        int b_ = tokb >> 10;
        #pragma unroll
        for (int n = 0; n < 4; ++n) {
            int o = n0 + wc * 64 + n * 16 + l15;
            float bias = (o < 1152) ? wq_b[o] : wkv_b[o - 1152];
            if (region == 0) {
                #pragma unroll
                for (int j = 0; j < 4; ++j) {
                    float y = acc[m][n][j] + bias;
                    qr[(size_t)(tokb + j) * DIM + o] = f2bf(fmaxf(y, 0.f));
                }
            } else {
                int oo = o - (region == 1 ? 1152 : 1536);
                size_t base = ((size_t)(b_ * 4 + oo / 96) * 96 + (oo % 96)) * 1024 + (tokb & 1023);
                ushort4v pk;
                #pragma unroll
                for (int j = 0; j < 4; ++j) {
                    float y = acc[m][n][j] + bias;
                    if (region == 1) y = fmaxf(y, 0.f);
                    pk[j] = f2bf(y);
                }
                if (region == 1) *(ushort4v*)(krT + base) = pk;
                else             *(ushort4v*)(vT + base) = pk;
            }
        }
    }
}

// ---------------- K2: focus norms -> scale factors ----------------
__global__ __launch_bounds__(1024) void norm_kernel(const ushort_t* __restrict__ qr,
                                                    const ushort_t* __restrict__ krT,
                                                    float* __restrict__ scale_q,
                                                    float* __restrict__ scale_k)
{
    int gblk = blockIdx.x, tid = threadIdx.x;
    float s2 = 0.f, s6 = 0.f;
    if (gblk < 192) {
        int b_ = gblk / 12, h = gblk % 12;
        const ushort_t* base = qr + (size_t)b_ * 1024 * DIM + h * 96;
        // 1024 rows x 12 ushort8 vectors per row
        for (int i = tid; i < 1024 * 12; i += 1024) {
            int nrow = i / 12, dv = (i - nrow * 12) * 8;
            ushort8 v = *(const ushort8*)(base + (size_t)nrow * DIM + dv);
            #pragma unroll
            for (int j = 0; j < 8; ++j) {
                float a = bf2f(v[j]);
                float a2 = a * a;
                s2 += a2; s6 += a2 * a2 * a2;
            }
        }
    } else {
        const ushort_t* base = krT + (size_t)(gblk - 192) * 96 * 1024;
        for (int i = tid; i < 96 * 1024 / 8; i += 1024) {
            ushort8 v = *(const ushort8*)(base + (size_t)i * 8);
            #pragma unroll
            for (int j = 0; j < 8; ++j) {
                float a = bf2f(v[j]);
                float a2 = a * a;
                s2 += a2; s6 += a2 * a2 * a2;
            }
        }
    }
    #pragma unroll
    for (int off = 32; off; off >>= 1) {
        s2 += __shfl_down(s2, off);
        s6 += __shfl_down(s6, off);
    }
    __shared__ float red[2][16];
    int lane = tid & 63, wave = tid >> 6;
    if (lane == 0) { red[0][wave] = s2; red[1][wave] = s6; }
    __syncthreads();
    if (tid == 0) {
        float t2 = 0.f, t6 = 0.f;
        #pragma unroll
        for (int w = 0; w < 16; ++w) { t2 += red[0][w]; t6 += red[1][w]; }
        float an = sqrtf(t2), ap = sqrtf(t6);
        if (ap == 0.f) ap = 1e-12f;
        float s = an / ap;
        if (gblk < 192) scale_q[gblk] = s; else scale_k[gblk - 192] = s;
    }
}

// ---------------- K3: kv = relu(k)^3^T @ v  (per b,kvh; partial over token chunks) ----------------
__global__ __launch_bounds__(384) void kv_kernel(const ushort_t* __restrict__ krT,
                                                 const ushort_t* __restrict__ vT,
                                                 float* __restrict__ kvbuf)
{
    int tid = threadIdx.x, lane = tid & 63, wave = tid >> 6;
    int nc = blockIdx.x, kvh = blockIdx.y, b_ = blockIdx.z;
    size_t base = (size_t)(b_ * 4 + kvh) * 96 * 1024;
    int l15 = lane & 15, gq = lane >> 4;
    f32x4 acc[6] = {};
    int d = wave * 16 + l15;
    const ushort_t* arow = krT + base + (size_t)d * 1024;
    for (int kt = 0; kt < 8; ++kt) {
        int n = nc * 256 + kt * 32 + gq * 8;
        ushort8 ar = *(const ushort8*)(arow + n);
        bf16x8 af;
        #pragma unroll
        for (int j = 0; j < 8; ++j) {
            float f = bf2f(ar[j]);
            af[j] = (short)f2bf(f * f * f);
        }
        #pragma unroll
        for (int e = 0; e < 6; ++e) {
            const ushort_t* brow = vT + base + (size_t)(e * 16 + l15) * 1024;
            ushort8 bu = *(const ushort8*)(brow + n);
            bf16x8 bfr = __builtin_bit_cast(bf16x8, bu);
            acc[e] = __builtin_amdgcn_mfma_f32_16x16x32_bf16(af, bfr, acc[e], 0, 0, 0);
        }
    }
    #pragma unroll
    for (int e = 0; e < 6; ++e) {
        int col = e * 16 + l15;
        #pragma unroll
        for (int j = 0; j < 4; ++j) {
            int row = wave * 16 + gq * 4 + j;
            atomicAdd(&kvbuf[((size_t)(b_ * 4 + kvh) * 96 + row) * 96 + col], acc[e][j]);
        }
    }
}

// ---------------- K4: depthwise 3x3 conv on v (channel-major grid) ----------------
__global__ __launch_bounds__(256) void dwconv_kernel(const ushort_t* __restrict__ vT,
                                                     const float* __restrict__ dwc_w,
                                                     const float* __restrict__ dwc_b,
                                                     ushort_t* __restrict__ cv)
{
    int c = blockIdx.x, b_ = blockIdx.y;
    const ushort_t* in = vT + (size_t)(b_ * 384 + c) * 1024;
    float w[9];
    #pragma unroll
    for (int i = 0; i < 9; ++i) w[i] = dwc_w[c * 9 + i];
    float bias = dwc_b[c];
    for (int p = threadIdx.x; p < 1024; p += 256) {
        int y = p >> 5, x = p & 31;
        float s = bias;
        #pragma unroll
        for (int ky = 0; ky < 3; ++ky) {
            int yy = y + ky - 1;
            if (yy < 0 || yy > 31) continue;
            #pragma unroll
            for (int kx = 0; kx < 3; ++kx) {
                int xx = x + kx - 1;
                if (xx < 0 || xx > 31) continue;
                s += w[ky * 3 + kx] * bf2f(in[yy * 32 + xx]);
            }
        }
        cv[(size_t)(b_ * 384 + c) * 1024 + p] = f2bf(s);
    }
}

// ---------------- K5: out = s * relu(q)^3 @ kv + conv ----------------
__global__ __launch_bounds__(256) void attn_kernel(const ushort_t* __restrict__ qr,
                                                   const float* __restrict__ kvbuf,
                                                   const ushort_t* __restrict__ cv,
                                                   const float* __restrict__ scale_q,
                                                   const float* __restrict__ scale_k,
                                                   ushort_t* __restrict__ obuf)
{
    __shared__ ushort_t BsT[96][104];   // kv^T as bf16: BsT[e][d]
    int tid = threadIdx.x, lane = tid & 63, wave = tid >> 6;
    int mt = blockIdx.x, h = blockIdx.y, b_ = blockIdx.z;
    int kvh = h & 3;
    const float* kvp = kvbuf + (size_t)(b_ * 4 + kvh) * 96 * 96;
    for (int i = tid; i < 96 * 96; i += 256) {
        int d = i / 96, e = i - d * 96;
        BsT[e][d] = f2bf(kvp[i]);
    }
    __syncthreads();
    int l15 = lane & 15, gq = lane >> 4;
    int t0 = mt * 128 + wave * 32;
    f32x4 acc[2][6] = {};
    for (int kt = 0; kt < 3; ++kt) {
        bf16x8 af[2];
        #pragma unroll
        for (int m = 0; m < 2; ++m) {
            int tok = t0 + m * 16 + l15;
            ushort8 ar = *(const ushort8*)(qr + (size_t)(b_ * 1024 + tok) * DIM + h * 96 + kt * 32 + gq * 8);
            #pragma unroll
            for (int j = 0; j < 8; ++j) {
                float f = bf2f(ar[j]);
                af[m][j] = (short)f2bf(f * f * f);
            }
        }
        #pragma unroll
        for (int n = 0; n < 6; ++n) {
            bf16x8 bfr = *(const bf16x8*)(&BsT[n * 16 + l15][kt * 32 + gq * 8]);
            #pragma unroll
            for (int m = 0; m < 2; ++m)
                acc[m][n] = __builtin_amdgcn_mfma_f32_16x16x32_bf16(af[m], bfr, acc[m][n], 0, 0, 0);
        }
    }
    float s = scale_q[b_ * 12 + h] * scale_k[b_ * 4 + kvh];
    #pragma unroll
    for (int m = 0; m < 2; ++m) {
        int tokb = t0 + m * 16 + gq * 4;
        #pragma unroll
        for (int n = 0; n < 6; ++n) {
            int e = n * 16 + l15;
            ushort4v c4 = *(const ushort4v*)(cv + ((size_t)(b_ * 384 + kvh * 96 + e)) * 1024 + tokb);
            #pragma unroll
            for (int j = 0; j < 4; ++j) {
                float val = acc[m][n][j] * s + bf2f(c4[j]);
                obuf[(size_t)(b_ * 1024 + tokb + j) * DIM + h * 96 + e] = f2bf(val);
            }
        }
    }
}

// ---------------- K6: final projection (f32 out) ----------------
__global__ __launch_bounds__(256) void proj_kernel(const ushort_t* __restrict__ obuf,
                                                   const ushort_t* __restrict__ projb,
                                                   const float* __restrict__ proj_b,
                                                   float* __restrict__ out)
{
    __shared__ ushort_t As[3 * 128 * 32];
    __shared__ ushort_t Bs[3 * 128 * 32];
    const int m0 = blockIdx.x * 128;
    const int n0 = blockIdx.y * 128;
    f32x4 acc[4][4] = {};
    gemm_main(obuf, projb, DIM, m0, n0, As, Bs, acc);

    const int tid = threadIdx.x;
    const int lane = tid & 63, wave = tid >> 6;
    const int wr = wave >> 1, wc = wave & 1;
    const int l15 = lane & 15, g = lane >> 4;
    #pragma unroll
    for (int m = 0; m < 4; ++m) {
        int tokb = m0 + wr * 64 + m * 16 + g * 4;
        #pragma unroll
        for (int n = 0; n < 4; ++n) {
            int o = n0 + wc * 64 + n * 16 + l15;
            float bias = proj_b[o];
            #pragma unroll
            for (int j = 0; j < 4; ++j)
                out[(size_t)(tokb + j) * DIM + o] = acc[m][n][j] + bias;
        }
    }
}

// ---------------- prep: f32 -> bf16 bulk converts ----------------
__global__ void cvt_f32_bf16(const float* __restrict__ src, ushort_t* __restrict__ dst, int n8)
{
    int i = blockIdx.x * 256 + threadIdx.x;
    if (i >= n8) return;
    const float4* s = (const float4*)src + (size_t)i * 2;
    float4 a = s[0], b4 = s[1];
    ushort8 o;
    o[0] = f2bf(a.x);  o[1] = f2bf(a.y);  o[2] = f2bf(a.z);  o[3] = f2bf(a.w);
    o[4] = f2bf(b4.x); o[5] = f2bf(b4.y); o[6] = f2bf(b4.z); o[7] = f2bf(b4.w);
    *(ushort8*)(dst + (size_t)i * 8) = o;
}

// all three weight matrices in one launch (segments in vec8 units)
#define SEG0 165888   // wq_w:   1152*1152/8
#define SEG1 276480   // + wkv_w: 768*1152/8
#define SEG2 442368   // + proj_w:1152*1152/8
__global__ void cvt_weights(const float* __restrict__ wq, const float* __restrict__ wkv,
                            const float* __restrict__ pw,
                            ushort_t* __restrict__ w1b, ushort_t* __restrict__ projb)
{
    int i = blockIdx.x * 256 + threadIdx.x;
    const float* src; ushort_t* dst; int j;
    if (i < SEG0)      { src = wq;  dst = w1b;                       j = i; }
    else if (i < SEG1) { src = wkv; dst = w1b + (size_t)DIM * DIM;   j = i - SEG0; }
    else if (i < SEG2) { src = pw;  dst = projb;                     j = i - SEG1; }
    else return;
    const float4* s = (const float4*)src + (size_t)j * 2;
    float4 a = s[0], b4 = s[1];
    ushort8 o;
    o[0] = f2bf(a.x);  o[1] = f2bf(a.y);  o[2] = f2bf(a.z);  o[3] = f2bf(a.w);
    o[4] = f2bf(b4.x); o[5] = f2bf(b4.y); o[6] = f2bf(b4.z); o[7] = f2bf(b4.w);
    *(ushort8*)(dst + (size_t)j * 8) = o;
}

extern "C" void kernel_launch(void* const* d_in, const int* in_sizes, int n_in,
                              void* d_out, int out_size, void* d_ws, size_t ws_size,
                              hipStream_t stream)
{
    const float* x      = (const float*)d_in[0];
    const float* wq_w   = (const float*)d_in[1];
    const float* wq_b   = (const float*)d_in[2];
    const float* wkv_w  = (const float*)d_in[3];
    const float* wkv_b  = (const float*)d_in[4];
    const float* dwc_w  = (const float*)d_in[5];
    const float* dwc_b  = (const float*)d_in[6];
    const float* proj_w = (const float*)d_in[7];
    const float* proj_b = (const float*)d_in[8];
    float* out = (float*)d_out;

    char* ws = (char*)d_ws;
    size_t off = 0;
    auto alloc = [&](size_t bytes) {
        void* p = ws + off;
        off += (bytes + 255) & ~(size_t)255;
        return p;
    };
    ushort_t* xb    = (ushort_t*)alloc((size_t)M_TOK * DIM * 2);   // reused as obuf later
    ushort_t* w1b   = (ushort_t*)alloc((size_t)O1 * DIM * 2);
    ushort_t* projb = (ushort_t*)alloc((size_t)DIM * DIM * 2);
    ushort_t* qr    = (ushort_t*)alloc((size_t)M_TOK * DIM * 2);
    ushort_t* krT   = (ushort_t*)alloc((size_t)BATCH * 4 * 96 * 1024 * 2);
    ushort_t* vT    = (ushort_t*)alloc((size_t)BATCH * 4 * 96 * 1024 * 2);
    float*    kvbuf = (float*)alloc((size_t)BATCH * 4 * 96 * 96 * 4);
    ushort_t* cv    = (ushort_t*)alloc((size_t)BATCH * 384 * 1024 * 2);
    float*    scale_q = (float*)alloc(192 * 4);
    float*    scale_k = (float*)alloc(64 * 4);
    ushort_t* obuf = xb;

    cvt_f32_bf16<<<(M_TOK * DIM / 8 + 255) / 256, 256, 0, stream>>>(x, xb, M_TOK * DIM / 8);
    cvt_weights<<<(SEG2 + 255) / 256, 256, 0, stream>>>(wq_w, wkv_w, proj_w, w1b, projb);
    hipMemsetAsync(kvbuf, 0, (size_t)BATCH * 4 * 96 * 96 * 4, stream);

    gemm1_kernel<<<dim3(M_TOK / 128, O1 / 128), 256, 0, stream>>>(xb, w1b, wq_b, wkv_b, qr, krT, vT);
    norm_kernel<<<256, 1024, 0, stream>>>(qr, krT, scale_q, scale_k);
    kv_kernel<<<dim3(4, 4, BATCH), 384, 0, stream>>>(krT, vT, kvbuf);
    dwconv_kernel<<<dim3(384, BATCH), 256, 0, stream>>>(vT, dwc_w, dwc_b, cv);
    attn_kernel<<<dim3(8, 12, BATCH), 256, 0, stream>>>(qr, kvbuf, cv, scale_q, scale_k, obuf);
    proj_kernel<<<dim3(M_TOK / 128, DIM / 128), 256, 0, stream>>>(obuf, projb, proj_b, out);
}